// Round 3
// baseline (178.523 us; speedup 1.0000x reference)
//
#include <hip/hip_runtime.h>
#include <stdint.h>

// Problem: out[m][n] = sum_k x[m][k] * w[n][k] + bias[n]
//   M=256, N=16384, K=4096, w = dequant(2-bit, group=16 along k)
// NOTE: harness dtype universe is {bf16, int32, float32}; the fp16
// weight_norm input arrives converted to float32.
#define M_DIM 256
#define N_DIM 16384
#define K_DIM 4096
#define BM 128
#define BN 64
#define BK 64

typedef __bf16 bf16x8 __attribute__((ext_vector_type(8)));
typedef float  f32x4  __attribute__((ext_vector_type(4)));

// fp32 -> bf16 bits, round-nearest-even (finite inputs)
__device__ __forceinline__ uint32_t f2bf(float f) {
  uint32_t u = __float_as_uint(f);
  return (u + 0x7fffu + ((u >> 16) & 1u)) >> 16;
}

// ---------------------------------------------------------------------------
// Kernel 1: x fp32 [256][4096] -> bf16 fragment-chunk order in workspace.
// Chunk = (m-block of 16 rows) x (k-chunk of 32): 64 slots x 16B.
// Slot L holds row (L&15), k = (L>>4)*8 .. +7  (MFMA 16x16x32 A-frag order).
// ws uint4 index = (mb_glob*128 + kch)*64 + L.
// ---------------------------------------------------------------------------
__global__ __launch_bounds__(256) void cvt_x_kernel(const float* __restrict__ x,
                                                    uint4* __restrict__ ws) {
  int T = blockIdx.x * 256 + threadIdx.x;       // 0..131071
  int mb_glob = T >> 13;                        // 16 m-blocks
  int r       = T & 8191;
  int kch     = r >> 6;                         // 128 k-chunks
  int L       = r & 63;
  int row = mb_glob * 16 + (L & 15);
  int k   = kch * 32 + (L >> 4) * 8;
  const float* p = x + (size_t)row * K_DIM + k;
  float4 a = *(const float4*)p;
  float4 b = *(const float4*)(p + 4);
  uint4 o;
  o.x = f2bf(a.x) | (f2bf(a.y) << 16);
  o.y = f2bf(a.z) | (f2bf(a.w) << 16);
  o.z = f2bf(b.x) | (f2bf(b.y) << 16);
  o.w = f2bf(b.z) | (f2bf(b.w) << 16);
  ws[T] = o;
}

// ---------------------------------------------------------------------------
// Kernel 2: 2-bit dequant + bf16 MFMA GEMM. Grid (N/64, M/128), 256 thr.
// Waves 2x2: wm = w>>1 (64 m-rows each), wn = w&1 (32 n-cols each).
// LDS fragment-chunk layout (slot index == consuming lane): conflict-free
// sequential ds_read_b128 / ds_write_b128.
// ---------------------------------------------------------------------------
__global__ __launch_bounds__(256, 2) void gemm2bit_kernel(
    const uint4*    __restrict__ aws,  // A chunks (see cvt)
    const uint32_t* __restrict__ q2,   // [G][4] packed 2-bit (low byte crumbs)
    const float*    __restrict__ nrm,  // [G] group norms (fp16 upconverted to f32 by harness)
    const float*    __restrict__ bias, // [N]
    float*          __restrict__ out)  // [256][16384] fp32
{
  __shared__ uint4 Ab[1024];  // 16 chunks (ts*8+mb) x 64 slots  = 16 KiB
  __shared__ uint4 Bb[512];   //  8 chunks (ts*4+nb) x 64 slots  =  8 KiB

  const int tid  = threadIdx.x;
  const int lane = tid & 63;
  const int w    = tid >> 6;
  const int wm   = w >> 1;
  const int wn   = w & 1;
  const int lo4  = lane & 15;
  const int qd   = lane >> 4;

  const int n0 = blockIdx.x * BN;
  const int m0 = blockIdx.y * BM;

  // B-staging role: one 16-elem group per thread
  const int snb  = tid >> 6;          // n-block 0..3 (= wave id)
  const int sqd  = (tid >> 4) & 3;    // k-group within 64 (0..3)
  const int slo4 = tid & 15;          // row within n-block
  const int grow = n0 + snb * 16 + slo4;

  f32x4 acc[4][2];
#pragma unroll
  for (int s = 0; s < 4; ++s)
#pragma unroll
    for (int u = 0; u < 2; ++u)
      acc[s][u] = (f32x4){0.f, 0.f, 0.f, 0.f};

  for (int kc = 0; kc < K_DIM; kc += BK) {
    __syncthreads();  // previous iteration's LDS reads done

    // ---- A staging: coalesced uint4 load from chunk-ordered ws -> LDS ----
#pragma unroll
    for (int j = 0; j < 4; ++j) {
      int s_lin = j * 256 + tid;          // 0..1023
      int ca = s_lin >> 6;                // chunk = ts*8 + mb
      int L  = s_lin & 63;
      int ts = ca >> 3, mb = ca & 7;
      uint4 g = aws[((size_t)(blockIdx.y * 8 + mb) * 128 + (kc >> 5) + ts) * 64 + L];
      Ab[ca * 64 + L] = g;
    }

    // ---- B staging: load group, dequant 16 elems, 2x ds_write_b128 ----
    {
      int gidx = grow * 256 + (kc >> 4) + sqd;
      uint4 q  = *(const uint4*)(q2 + (size_t)gidx * 4);
      float nv = nrm[gidx];
      float a  = nv * (2.0f / 3.0f);
      float b  = -nv;
      uint32_t res[8];
#pragma unroll
      for (int p = 0; p < 4; ++p) {        // element e = p*4 + i (i = shift)
        uint32_t qq = (&q.x)[p];
        float f0 = fmaf((float)(qq & 3u), a, b);
        float f1 = fmaf((float)((qq >> 2) & 3u), a, b);
        float f2 = fmaf((float)((qq >> 4) & 3u), a, b);
        float f3 = fmaf((float)((qq >> 6) & 3u), a, b);
        res[p * 2]     = f2bf(f0) | (f2bf(f1) << 16);
        res[p * 2 + 1] = f2bf(f2) | (f2bf(f3) << 16);
      }
      // group k-range = sqd*16..+15 -> chunk ts = sqd>>1, half = sqd&1
      int cb   = (sqd >> 1) * 4 + snb;
      int base = cb * 64 + (sqd & 1) * 32 + slo4;
      Bb[base]      = make_uint4(res[0], res[1], res[2], res[3]);  // e 0..7
      Bb[base + 16] = make_uint4(res[4], res[5], res[6], res[7]);  // e 8..15
    }

    __syncthreads();

    // ---- compute: 2 k-steps of 32; 8 MFMAs per step per wave ----
#pragma unroll
    for (int ts = 0; ts < 2; ++ts) {
      bf16x8 af[4], bf[2];
#pragma unroll
      for (int s = 0; s < 4; ++s)
        af[s] = *(const bf16x8*)&Ab[(ts * 8 + wm * 4 + s) * 64 + lane];
#pragma unroll
      for (int u = 0; u < 2; ++u)
        bf[u] = *(const bf16x8*)&Bb[(ts * 4 + wn * 2 + u) * 64 + lane];
#pragma unroll
      for (int s = 0; s < 4; ++s)
#pragma unroll
        for (int u = 0; u < 2; ++u)
          acc[s][u] = __builtin_amdgcn_mfma_f32_16x16x32_bf16(
              af[s], bf[u], acc[s][u], 0, 0, 0);
    }
  }

  // ---- epilogue: C/D layout col=lane&15 (n), row=(lane>>4)*4+reg (m) ----
  float bv[2];
#pragma unroll
  for (int u = 0; u < 2; ++u)
    bv[u] = bias[n0 + wn * 32 + u * 16 + lo4];

#pragma unroll
  for (int s = 0; s < 4; ++s) {
    int mrow = m0 + wm * 64 + s * 16 + qd * 4;
#pragma unroll
    for (int u = 0; u < 2; ++u) {
      int ncol = n0 + wn * 32 + u * 16 + lo4;
      float* p = out + (size_t)mrow * N_DIM + ncol;
#pragma unroll
      for (int r = 0; r < 4; ++r)
        p[(size_t)r * N_DIM] = acc[s][u][r] + bv[u];
    }
  }
}

// ---------------------------------------------------------------------------
extern "C" void kernel_launch(void* const* d_in, const int* in_sizes, int n_in,
                              void* d_out, int out_size, void* d_ws, size_t ws_size,
                              hipStream_t stream) {
  const float*    x    = (const float*)d_in[0];
  const uint32_t* q2   = (const uint32_t*)d_in[1];
  const float*    nm   = (const float*)d_in[2];
  const float*    bias = (const float*)d_in[3];
  float*          out  = (float*)d_out;
  uint4*          aws  = (uint4*)d_ws;   // 2 MiB: x as bf16 fragment chunks

  cvt_x_kernel<<<512, 256, 0, stream>>>(x, aws);

  dim3 grid(N_DIM / BN, M_DIM / BM);
  gemm2bit_kernel<<<grid, 256, 0, stream>>>(aws, q2, nm, bias, out);
}